// Round 10
// baseline (122.936 us; speedup 1.0000x reference)
//
#include <hip/hip_runtime.h>
#include <hip/hip_bf16.h>
#include <cstdint>

#define BATCH   32
#define NVARS   16
#define SAMPLES 4096
#define EDIM    128
#define NTOK    1016          // (4096-32)/4
#define PLELEM  4368          // bf16 per plane slot = 8736 B (16B-aligned)

typedef __bf16 bf8_t __attribute__((ext_vector_type(8)));
typedef float  f4_t  __attribute__((ext_vector_type(4)));

// ---------------------------------------------------------------------------
// prep_kernel: W_patch repack ONLY.
// WtF[kb][g(8)][lane(64)][t(8)] = B[kbase(kb)+quad*8+t][g*16+l15]
//   (kbase=(4*dlt+(s&3))*128+(s>>2)*32, kb=s*8+dlt) -> a GEMM wave's
//   B-fragment group is one coalesced 1KB global load straight to VGPRs.
// ---------------------------------------------------------------------------
__global__ __launch_bounds__(256) void prep_kernel(
    const float* __restrict__ Wp, __hip_bfloat16* __restrict__ WtF)
{
  __shared__ float ls[32][132];
  int tid = threadIdx.x;
  int kb  = blockIdx.x;
  int s = kb >> 3, dlt = kb & 7;
  int kbase = (4 * dlt + (s & 3)) * 128 + (s >> 2) * 32;
#pragma unroll
  for (int r = 0; r < 16; ++r) {
    int idx = tid + r * 256;
    ls[idx >> 7][idx & 127] =
        Wp[(size_t)(kbase + (idx >> 7)) * EDIM + (idx & 127)];
  }
  __syncthreads();
  int g = tid >> 5, l5 = tid & 31;
#pragma unroll
  for (int h = 0; h < 2; ++h) {
    int lane = l5 + h * 32;
    int quad = lane >> 4, l15 = lane & 15;
    int n = g * 16 + l15;
    union { unsigned short u[8]; uint4 v; } pk;
#pragma unroll
    for (int t = 0; t < 8; ++t) {
      __hip_bfloat16 hh = __float2bfloat16(ls[quad * 8 + t][n]);
      pk.u[t] = *(unsigned short*)&hh;
    }
    *(uint4*)(WtF + (size_t)kb * 4096 + g * 512 + lane * 8) = pk.v;
  }
}

// ---------------------------------------------------------------------------
// R10 = R7 structure + amdgpu_waves_per_eu(4,4) to force the 128-VGPR budget.
// R7/R8 post-mortem: bare __launch_bounds__(1024[,4]) leaves the allocator
// targeting 8 waves/EU -> 64-VGPR cap -> ~110 MB/dispatch scratch spills
// (the 2nd launch-bounds arg is a MINIMUM; it cannot lower the target).
// amdgpu_waves_per_eu(4,4) pins min=max=4 waves/EU -> 512/4 = 128 VGPRs.
// R9 post-mortem: 2 blocks/CU at 64-token tiles doubled B-L2 traffic/CU
// (1->2 MB, +7.4 us measured vs +7.8 predicted) - occupancy must come from
// ONE block.  This kernel: 1 block/CU, 16 waves = 4 waves/SIMD, B=1MB/CU,
// encode LDS unchanged (2-row-broadcast tasks, 1088 b128/CU).
//
// Structure recap (R7): phase-split fusion; 16 waves = 4 K-quarters (g2)
// x 2 N-halves (nh) x 2 M-halves (mh); wave tile 64x64, acc[4][4]=64 regs;
// af[4] single-buffer (TLP replaces ILP); bq depth-2; encode 4.25
// tasks/thread; barrier-free GEMM; 4-partial LDS reduction epilogue.
// GEMM live = 64 acc + 16 af + 32 bq + ~12 addr ~= 124 <= 128; encode live
// ~90, phase-disjoint.  K-order, swizzle, summation order identical to
// R0-verified math (mh*64 and i*16 drop out of swz mod 4).
// ---------------------------------------------------------------------------
__global__
__attribute__((amdgpu_flat_work_group_size(1024, 1024)))
__attribute__((amdgpu_waves_per_eu(4, 4)))
void fused_kernel(
    const float* __restrict__ x,
    const float* __restrict__ Ws,
    const float* __restrict__ bs,
    const __hip_bfloat16* __restrict__ WtF,
    const float* __restrict__ bp,
    float* __restrict__ out)
{
  __shared__ __align__(16) __hip_bfloat16 Apan[16 * PLELEM];  // 139,776 B
  __shared__ __align__(16) float xTp[2][136][16];             //  17,408 B

  int tid  = threadIdx.x;
  int lane = tid & 63;
  int wv   = tid >> 6;               // 0..15
  int g2   = wv >> 2;                // K-quarter 0..3
  int nh   = (wv >> 1) & 1;          // N-half
  int mh   = wv & 1;                 // M-half
  int b    = blockIdx.x >> 3;
  int t0   = (blockIdx.x & 7) << 7;
  int quad = lane >> 4;
  int l15  = lane & 15;

  const __hip_bfloat16* bg = WtF + (size_t)(nh * 4) * 512 + lane * 8;

  // ---------------- encode setup: fixed dim-quad per thread --------------
  int q4 = tid & 31;                 // dims 4*q4 .. 4*q4+3
  int eq = q4 >> 3;                  // e-block 0..3
  int cq = (q4 >> 1) & 3;            // 16B chunk within row
  int hq = q4 & 1;                   // 8B half within chunk
  int r0 = tid >> 5;                 // 0..31 (row base, +32j)

  float w[NVARS][4];
  float bz[4];
  {
    int d0 = q4 * 4;
#pragma unroll
    for (int v = 0; v < NVARS; ++v)
      *(float4*)&w[v][0] = *(const float4*)(Ws + v * EDIM + d0);
    *(float4*)&bz[0] = *(const float4*)(bs + d0);
  }

  // ---------------- x -> regs: (row, var), float4 = 4 phases -------------
  int vv = tid & 15, rr = tid >> 4;  // rr 0..63
  float4 xreg[3];
  {
    const float* xb = x + ((size_t)b * NVARS + vv) * SAMPLES;
    xreg[0] = *(const float4*)(xb + (t0 + rr) * 4);
    xreg[1] = *(const float4*)(xb + (t0 + 64 + rr) * 4);
    if (tid < 128) {                             // rows 128..135 (rr<8)
      int s4 = (t0 + 128 + rr) * 4;
      if (s4 > SAMPLES - 4) s4 = SAMPLES - 4;    // clamp (masked tokens only)
      xreg[2] = *(const float4*)(xb + s4);
    }
  }

  // ---------------- phase staging + encode -------------------------------
  auto stageX = [&](int p, int buf) {
    float c0 = (p == 0) ? xreg[0].x : (p == 1) ? xreg[0].y
             : (p == 2) ? xreg[0].z : xreg[0].w;
    float c1 = (p == 0) ? xreg[1].x : (p == 1) ? xreg[1].y
             : (p == 2) ? xreg[1].z : xreg[1].w;
    xTp[buf][rr][vv]      = c0;
    xTp[buf][64 + rr][vv] = c1;
    if (tid < 128) {
      float c2 = (p == 0) ? xreg[2].x : (p == 1) ? xreg[2].y
               : (p == 2) ? xreg[2].z : xreg[2].w;
      xTp[buf][128 + rr][vv] = c2;
    }
  };

  auto encTask = [&](int p, int buf, int r) {
    const float* xr = &xTp[buf][r][0];
    float xv[NVARS];
    *(float4*)&xv[0]  = *(const float4*)(xr + 0);
    *(float4*)&xv[4]  = *(const float4*)(xr + 4);
    *(float4*)&xv[8]  = *(const float4*)(xr + 8);
    *(float4*)&xv[12] = *(const float4*)(xr + 12);
    float a0 = bz[0], a1 = bz[1], a2 = bz[2], a3 = bz[3];
#pragma unroll
    for (int v = 0; v < NVARS; ++v) {
      a0 += xv[v] * w[v][0]; a1 += xv[v] * w[v][1];
      a2 += xv[v] * w[v][2]; a3 += xv[v] * w[v][3];
    }
    union { unsigned short us[4]; uint2 q; } pk;
    pk.us[0] = (unsigned short)(__float_as_uint(floorf(a0)) >> 16);
    pk.us[1] = (unsigned short)(__float_as_uint(floorf(a1)) >> 16);
    pk.us[2] = (unsigned short)(__float_as_uint(floorf(a2)) >> 16);
    pk.us[3] = (unsigned short)(__float_as_uint(floorf(a3)) >> 16);
    int phys = (cq + (r >> 1)) & 3;              // t0 contributes 0 mod 4
    char* plbase = (char*)&Apan[(eq * 4 + p) * PLELEM];
    *(uint2*)(plbase + r * 64 + phys * 16 + hq * 8) = pk.q;
  };

  stageX(0, 0);
  __syncthreads();
#pragma unroll
  for (int p = 0; p < 4; ++p) {
    if (p < 3) stageX(p + 1, (p + 1) & 1);
    int buf = p & 1;
#pragma unroll
    for (int j = 0; j < 4; ++j) encTask(p, buf, r0 + 32 * j);
    if (tid < 256) encTask(p, buf, 128 + (tid >> 5));
    __syncthreads();
  }
  // panel fully resident; no further A traffic, no barriers until epilogue

  // ---------------- GEMM main loop (barrier-free, 4K x 2N x 2M) ----------
  f4_t acc[4][4];
  f4_t zero = {0.f, 0.f, 0.f, 0.f};
#pragma unroll
  for (int i = 0; i < 4; ++i)
#pragma unroll
    for (int j = 0; j < 4; ++j) acc[i][j] = zero;

  auto loadB = [&](int kb, uint4* d) {
#pragma unroll
    for (int j = 0; j < 4; ++j)
      d[j] = *(const uint4*)(bg + (size_t)kb * 4096 + j * 512);
  };

  auto loadAF = [&](bf8_t* af, const bf8_t* pA, int dlt) {
    int swz = (quad + ((t0 + mh * 64 + dlt + l15) >> 1)) & 3;
#pragma unroll
    for (int i = 0; i < 4; ++i)
      af[i] = pA[(mh * 64 + dlt + i * 16 + l15) * 4 + swz];
  };

  auto mstep = [&](const bf8_t* af, const uint4* bq_) {
    __builtin_amdgcn_s_setprio(1);
#pragma unroll
    for (int mi = 0; mi < 4; ++mi)
#pragma unroll
      for (int ni = 0; ni < 4; ++ni)
        acc[mi][ni] = __builtin_amdgcn_mfma_f32_16x16x32_bf16(
            af[mi], __builtin_bit_cast(bf8_t, bq_[ni]), acc[mi][ni], 0, 0, 0);
    __builtin_amdgcn_s_setprio(0);
  };

  bf8_t af[4];
  uint4 bq[2][4];
  loadB(g2 * 32 + 0, bq[0]);
  loadB(g2 * 32 + 1, bq[1]);

  for (int ss = 0; ss < 4; ++ss) {
    const bf8_t* pA = (const bf8_t*)&Apan[(g2 * 4 + ss) * PLELEM];
#pragma unroll
    for (int d = 0; d < 8; ++d) {
      int kl = ss * 8 + d;
      loadAF(af, pA, d);
      mstep(af, bq[d & 1]);
      if (kl < 30) loadB(g2 * 32 + kl + 2, bq[d & 1]);
    }
  }

  // ---- 4-partial K reduction (g2 1..3 -> g2 0) + fused epilogue ----
  // rb2: 768 slots x 20 floats over Apan (61,440 B).  1 mi per round,
  // 4 rounds.  Writers: 12 waves (g2>0); readers: 4 waves (g2==0).
  float* rb2 = (float*)&Apan[0];
  int idx4 = nh * 2 + mh;
  float bias[4];
#pragma unroll
  for (int ni = 0; ni < 4; ++ni) bias[ni] = bp[(nh << 6) + ni * 16 + l15];

#pragma unroll
  for (int rd = 0; rd < 4; ++rd) {
    __syncthreads();
    if (g2 > 0) {
      int slot = ((g2 - 1) * 4 + idx4) * 64 + lane;
#pragma unroll
      for (int ni = 0; ni < 4; ++ni)
        *(f4_t*)&rb2[(size_t)slot * 20 + ni * 4] = acc[rd][ni];
    }
    __syncthreads();
    if (g2 == 0) {
      f4_t s0 = acc[rd][0], s1 = acc[rd][1];
      f4_t s2 = acc[rd][2], s3 = acc[rd][3];
#pragma unroll
      for (int q = 1; q < 4; ++q) {
        int sl = ((q - 1) * 4 + idx4) * 64 + lane;
        s0 += *(const f4_t*)&rb2[(size_t)sl * 20 + 0];
        s1 += *(const f4_t*)&rb2[(size_t)sl * 20 + 4];
        s2 += *(const f4_t*)&rb2[(size_t)sl * 20 + 8];
        s3 += *(const f4_t*)&rb2[(size_t)sl * 20 + 12];
      }
      f4_t sv[4] = {s0, s1, s2, s3};
#pragma unroll
      for (int ni = 0; ni < 4; ++ni)
#pragma unroll
        for (int r = 0; r < 4; ++r) {
          int t = t0 + mh * 64 + rd * 16 + quad * 4 + r;
          if (t < NTOK) {
            int n = (nh << 6) + ni * 16 + l15;
            out[((size_t)b * NTOK + t) * EDIM + n] =
                floorf(sv[ni][r] + bias[ni]);
          }
        }
    }
  }
}

// ---------------------------------------------------------------------------
extern "C" void kernel_launch(void* const* d_in, const int* in_sizes, int n_in,
                              void* d_out, int out_size, void* d_ws, size_t ws_size,
                              hipStream_t stream) {
  const float* x  = (const float*)d_in[0];
  const float* Ws = (const float*)d_in[1];
  const float* bs = (const float*)d_in[2];
  const float* Wp = (const float*)d_in[3];
  const float* bp = (const float*)d_in[4];
  float* out = (float*)d_out;

  __hip_bfloat16* WtF = (__hip_bfloat16*)d_ws;   // 1 MB fragment-major B

  prep_kernel<<<128, 256, 0, stream>>>(Wp, WtF);
  fused_kernel<<<BATCH * 8, 1024, 0, stream>>>(x, Ws, bs, WtF, bp, out);
}

// Round 11
// 115.055 us; speedup vs baseline: 1.0685x; 1.0685x over previous
//
#include <hip/hip_runtime.h>
#include <hip/hip_bf16.h>
#include <cstdint>

#define BATCH   32
#define NVARS   16
#define SAMPLES 4096
#define EDIM    128
#define NTOK    1016          // (4096-32)/4
#define PLELEM  4368          // bf16 per plane slot = 8736 B (16B-aligned)

typedef __bf16 bf8_t __attribute__((ext_vector_type(8)));
typedef float  f4_t  __attribute__((ext_vector_type(4)));

// ---------------------------------------------------------------------------
// prep_kernel: W_patch repack ONLY.
// WtF[kb][g(8)][lane(64)][t(8)] = B[kbase(kb)+quad*8+t][g*16+l15]
//   (kbase=(4*dlt+(s&3))*128+(s>>2)*32, kb=s*8+dlt) -> a GEMM wave's
//   B-fragment group is one coalesced 1KB global load straight to VGPRs.
// ---------------------------------------------------------------------------
__global__ __launch_bounds__(256) void prep_kernel(
    const float* __restrict__ Wp, __hip_bfloat16* __restrict__ WtF)
{
  __shared__ float ls[32][132];
  int tid = threadIdx.x;
  int kb  = blockIdx.x;
  int s = kb >> 3, dlt = kb & 7;
  int kbase = (4 * dlt + (s & 3)) * 128 + (s >> 2) * 32;
#pragma unroll
  for (int r = 0; r < 16; ++r) {
    int idx = tid + r * 256;
    ls[idx >> 7][idx & 127] =
        Wp[(size_t)(kbase + (idx >> 7)) * EDIM + (idx & 127)];
  }
  __syncthreads();
  int g = tid >> 5, l5 = tid & 31;
#pragma unroll
  for (int h = 0; h < 2; ++h) {
    int lane = l5 + h * 32;
    int quad = lane >> 4, l15 = lane & 15;
    int n = g * 16 + l15;
    union { unsigned short u[8]; uint4 v; } pk;
#pragma unroll
    for (int t = 0; t < 8; ++t) {
      __hip_bfloat16 hh = __float2bfloat16(ls[quad * 8 + t][n]);
      pk.u[t] = *(unsigned short*)&hh;
    }
    *(uint4*)(WtF + (size_t)kb * 4096 + g * 512 + lane * 8) = pk.v;
  }
}

// ---------------------------------------------------------------------------
// R11: producer-consumer wave specialization (512 thr, (512,2) = the only
// toolchain config proven to give the 128+128 unified budget; R7/R8/R10
// showed 1024-thr blocks are hard-capped at 64 VGPR).
//
// 8 waves: wv 0..3 = GEMM (g = wv>>1 K-half, nh = wv&1 N-half; wave tile
// M=128 x N=64, acc[8][4] in AGPRs; B traffic 1 MB/CU, streams disjoint);
// wv 4..7 = ENCODE (17 tasks/thread/phase; w/bz reloaded per region from
// L2 so NOTHING encode-side is loop-carried -> static regs = acc(128 AGPR)
// + max(branch locals ~110 arch) ~= 238 <= 256).
//
// Phase pipeline, 1 barrier per region:
//   region p: enc { stageX(p+1) direct-from-global; reload w; encode
//                   phase p -> planes (e,p) all e }
//             gemm{ superstep ss=p-1: 16 kb = s in {8g+ss, 8g+4+ss},
//                   planes (2g)*4+ss and (2g+1)*4+ss }
// Race-free: encP(p) writes planes (.,p); concurrent GEMM reads (.,p-1).
// Per SIMD: 1 MFMA-heavy + 1 VALU-heavy wave -> complementary pipes.
// kb->plane identity (s=kb>>3, e=s>>2, p=s&3) = R0-verified mapping; only
// the f32 partial-sum grouping reassociates (as in every prior split).
// Epilogue: single-pass 2-partial reduction (g=1 dumps acc[8][4] to LDS
// stride-20, g=0 adds + floor + store); enc waves just hit the barriers.
// ---------------------------------------------------------------------------
__global__ __launch_bounds__(512, 2) void fused_kernel(
    const float* __restrict__ x,
    const float* __restrict__ Ws,
    const float* __restrict__ bs,
    const __hip_bfloat16* __restrict__ WtF,
    const float* __restrict__ bp,
    float* __restrict__ out)
{
  __shared__ __align__(16) __hip_bfloat16 Apan[16 * PLELEM];  // 139,776 B
  __shared__ __align__(16) float xTp[2][136][16];             //  17,408 B

  int tid  = threadIdx.x;
  int lane = tid & 63;
  int wv   = tid >> 6;               // 0..7
  bool isenc = (wv >= 4);
  int b    = blockIdx.x >> 3;
  int t0   = (blockIdx.x & 7) << 7;
  int quad = lane >> 4;
  int l15  = lane & 15;

  // ---- GEMM wave ids (wv 0..3) ----
  int g  = wv >> 1;                  // K-half
  int nh = wv & 1;                   // N-half
  const __hip_bfloat16* bg = WtF + (size_t)(nh * 4) * 512 + lane * 8;

  // ---- ENC wave ids (wv 4..7) ----
  int et = tid & 255;
  int q4 = et & 31;                  // dim-quad: dims 4*q4..4*q4+3
  int eq = q4 >> 3, cq = (q4 >> 1) & 3, hq = q4 & 1;
  int r0 = et >> 5;                  // 0..7 (task rows r0+8j, j<17)
  int vv = et & 15, rr = et >> 4;    // stage: var vv, rows rr+16j

  // ---------------- encode helpers (all state region-local) --------------
  float w[NVARS][4], bz[4];
  auto loadW = [&]() {
    int d0 = q4 * 4;
#pragma unroll
    for (int v = 0; v < NVARS; ++v)
      *(float4*)&w[v][0] = *(const float4*)(Ws + v * EDIM + d0);
    *(float4*)&bz[0] = *(const float4*)(bs + d0);
  };

  auto stageX = [&](int p, int buf) {    // direct global->LDS, 9 scalars
    const float* xb = x + ((size_t)b * NVARS + vv) * SAMPLES;
#pragma unroll
    for (int j = 0; j < 8; ++j) {
      int row = rr + 16 * j;                       // 0..127
      xTp[buf][row][vv] = xb[(t0 + row) * 4 + p];  // max idx 4095: in-bounds
    }
    if (et < 128) {
      int row = 128 + rr;
      int sidx = (t0 + row) * 4 + p;
      if (sidx > SAMPLES - 1) sidx = SAMPLES - 1;  // clamp (masked tokens)
      xTp[buf][row][vv] = xb[sidx];
    }
  };

  auto encTask = [&](int p, int buf, int r) {
    const float* xr = &xTp[buf][r][0];
    float xv[NVARS];
    *(float4*)&xv[0]  = *(const float4*)(xr + 0);
    *(float4*)&xv[4]  = *(const float4*)(xr + 4);
    *(float4*)&xv[8]  = *(const float4*)(xr + 8);
    *(float4*)&xv[12] = *(const float4*)(xr + 12);
    float a0 = bz[0], a1 = bz[1], a2 = bz[2], a3 = bz[3];
#pragma unroll
    for (int v = 0; v < NVARS; ++v) {
      a0 += xv[v] * w[v][0]; a1 += xv[v] * w[v][1];
      a2 += xv[v] * w[v][2]; a3 += xv[v] * w[v][3];
    }
    union { unsigned short us[4]; uint2 q; } pk;
    pk.us[0] = (unsigned short)(__float_as_uint(floorf(a0)) >> 16);
    pk.us[1] = (unsigned short)(__float_as_uint(floorf(a1)) >> 16);
    pk.us[2] = (unsigned short)(__float_as_uint(floorf(a2)) >> 16);
    pk.us[3] = (unsigned short)(__float_as_uint(floorf(a3)) >> 16);
    int phys = (cq + (r >> 1)) & 3;              // t0 contributes 0 mod 4
    char* plbase = (char*)&Apan[(eq * 4 + p) * PLELEM];
    *(uint2*)(plbase + r * 64 + phys * 16 + hq * 8) = pk.q;
  };

  // ---------------- GEMM helpers (acc loop-carried, rest ss-local) -------
  f4_t acc[8][4];
  if (!isenc) {
    f4_t zero = {0.f, 0.f, 0.f, 0.f};
#pragma unroll
    for (int i = 0; i < 8; ++i)
#pragma unroll
      for (int j = 0; j < 4; ++j) acc[i][j] = zero;
  }

  auto loadB = [&](int kb, uint4* d) {
#pragma unroll
    for (int j = 0; j < 4; ++j)
      d[j] = *(const uint4*)(bg + (size_t)kb * 4096 + j * 512);
  };
  auto loadAF0 = [&](bf8_t* af, const bf8_t* pA, int dlt) {
    int swz = (quad + ((t0 + dlt + l15) >> 1)) & 3;
#pragma unroll
    for (int i = 0; i < 4; ++i)
      af[i] = pA[(dlt + i * 16 + l15) * 4 + swz];
  };
  auto loadAF1 = [&](bf8_t* af, const bf8_t* pA, int dlt) {
    int swz = (quad + ((t0 + dlt + l15) >> 1)) & 3;
#pragma unroll
    for (int i = 0; i < 4; ++i)
      af[i] = pA[(dlt + (i + 4) * 16 + l15) * 4 + swz];
  };
  auto mstepH = [&](const bf8_t* af, const uint4* bq_, int mibase) {
    __builtin_amdgcn_s_setprio(1);
#pragma unroll
    for (int mi = 0; mi < 4; ++mi)
#pragma unroll
      for (int ni = 0; ni < 4; ++ni)
        acc[mibase + mi][ni] = __builtin_amdgcn_mfma_f32_16x16x32_bf16(
            af[mi], __builtin_bit_cast(bf8_t, bq_[ni]),
            acc[mibase + mi][ni], 0, 0, 0);
    __builtin_amdgcn_s_setprio(0);
  };

  auto gemmSS = [&](int ss) {
    const bf8_t* plA = (const bf8_t*)&Apan[((2 * g) * 4 + ss) * PLELEM];
    const bf8_t* plB = (const bf8_t*)&Apan[((2 * g + 1) * 4 + ss) * PLELEM];
    int kb0 = (8 * g + ss) * 8;          // e=2g  , p=ss
    int kb1 = (8 * g + 4 + ss) * 8;      // e=2g+1, p=ss
    uint4 bq[2][4];
    loadB(kb0 + 0, bq[0]);
    loadB(kb0 + 1, bq[1]);
    bf8_t af0[4], af1[4];
    loadAF0(af0, plA, 0);
#pragma unroll
    for (int dd = 0; dd < 16; ++dd) {
      const bf8_t* pc = (dd < 8) ? plA : plB;
      int dlt = dd & 7;
      loadAF1(af1, pc, dlt);
      mstepH(af0, bq[dd & 1], 0);
      if (dd < 15) {
        const bf8_t* pn = (dd + 1 < 8) ? plA : plB;
        loadAF0(af0, pn, (dd + 1) & 7);
      }
      mstepH(af1, bq[dd & 1], 4);
      int nk = dd + 2;
      if (nk < 16) loadB((nk < 8 ? kb0 : kb1) + (nk & 7), bq[dd & 1]);
    }
  };

  // ---------------- pipelined main flow ----------------------------------
  if (isenc) stageX(0, 0);
  __syncthreads();                                   // xT[0] ready

#pragma unroll
  for (int p = 0; p < 4; ++p) {
    if (isenc) {
      if (p < 3) stageX(p + 1, (p + 1) & 1);         // other buffer: no race
      loadW();
#pragma unroll
      for (int j = 0; j < 17; ++j) encTask(p, p & 1, r0 + 8 * j);
    } else if (p > 0) {
      gemmSS(p - 1);                                 // planes (.,p-1) ready
    }
    __syncthreads();                                 // planes (.,p) ready
  }
  if (!isenc) gemmSS(3);

  // ---- 2-partial K reduction (g=1 -> g=0) + fused epilogue --------------
  // rb idx = (mi*128 + nh*64 + lane)*20 + ni*4: lane-stride 20 floats ->
  // 2-way bank alias (free); 81,920 B over Apan (planes done being read).
  float* rb = (float*)&Apan[0];
  __syncthreads();
  if (!isenc && g == 1) {
#pragma unroll
    for (int mi = 0; mi < 8; ++mi)
#pragma unroll
      for (int ni = 0; ni < 4; ++ni)
        *(f4_t*)&rb[(size_t)(mi * 128 + nh * 64 + lane) * 20 + ni * 4] =
            acc[mi][ni];
  }
  __syncthreads();
  if (!isenc && g == 0) {
    float bias[4];
#pragma unroll
    for (int ni = 0; ni < 4; ++ni) bias[ni] = bp[nh * 64 + ni * 16 + l15];
#pragma unroll
    for (int mi = 0; mi < 8; ++mi) {
      f4_t sv[4];
#pragma unroll
      for (int ni = 0; ni < 4; ++ni)
        sv[ni] = acc[mi][ni] +
            *(const f4_t*)&rb[(size_t)(mi * 128 + nh * 64 + lane) * 20 + ni * 4];
#pragma unroll
      for (int ni = 0; ni < 4; ++ni)
#pragma unroll
        for (int r = 0; r < 4; ++r) {
          int t = t0 + mi * 16 + quad * 4 + r;
          if (t < NTOK) {
            int n = nh * 64 + ni * 16 + l15;
            out[((size_t)b * NTOK + t) * EDIM + n] =
                floorf(sv[ni][r] + bias[ni]);
          }
        }
    }
  }
}

// ---------------------------------------------------------------------------
extern "C" void kernel_launch(void* const* d_in, const int* in_sizes, int n_in,
                              void* d_out, int out_size, void* d_ws, size_t ws_size,
                              hipStream_t stream) {
  const float* x  = (const float*)d_in[0];
  const float* Ws = (const float*)d_in[1];
  const float* bs = (const float*)d_in[2];
  const float* Wp = (const float*)d_in[3];
  const float* bp = (const float*)d_in[4];
  float* out = (float*)d_out;

  __hip_bfloat16* WtF = (__hip_bfloat16*)d_ws;   // 1 MB fragment-major B

  prep_kernel<<<128, 256, 0, stream>>>(Wp, WtF);
  fused_kernel<<<BATCH * 8, 512, 0, stream>>>(x, Ws, bs, WtF, bp, out);
}